// Round 4
// baseline (244.243 us; speedup 1.0000x reference)
//
#include <hip/hip_runtime.h>
#include <math.h>

#define BB 16
#define QQ 300
#define CC 256
#define NHH 8
#define DHH 32
#define SUMPP 16
#define SSS 8500
#define GQ 10
#define QT (QQ / GQ) // 30

// ---------------------------------------------------------------------------
// Kernel A: offsets GEMM + attn GEMM + softmax. Unchanged from R3 (~10us,
// near its VALU floor: 0.94 GFLOP, block-uniform hs -> s_load operands).
// ---------------------------------------------------------------------------
__global__ __launch_bounds__(384) void precompute_kernel(
    const float* __restrict__ hs,      // (B,Q,C)
    const float* __restrict__ refp,    // (B,Q,1,4)
    const float* __restrict__ off_k,   // (C,256)
    const float* __restrict__ off_b,   // 256
    const float* __restrict__ attn_k,  // (C,128)
    const float* __restrict__ attn_b,  // 128
    const float* __restrict__ nps,     // 16
    float* __restrict__ loc_t,         // ws: (B,Q,128,2) in [p*8+h][xy]
    float* __restrict__ aw_t,          // ws: (B,Q,128)   in [p*8+h]
    float* __restrict__ attn_out)      // d_out: (B,Q,NH,SUMP) = [h][p]
{
    const int t = threadIdx.x;
    const int blk = blockIdx.x;            // 0..B*QT-1
    const int b = blk / QT;
    const int q0 = (blk % QT) * GQ;
    const float* hsb = hs + ((size_t)b * QQ + q0) * CC;

    float acc[GQ];
#pragma unroll
    for (int g = 0; g < GQ; ++g) acc[g] = 0.f;

    if (t < 256) {
        const int h = t >> 5;
        const int p = (t >> 1) & 15;
        const int xy = t & 1;
        const float* kcol = off_k + t;
#pragma unroll 8
        for (int c = 0; c < CC; ++c) {
            const float k = kcol[c * 256];
#pragma unroll
            for (int g = 0; g < GQ; ++g)
                acc[g] = fmaf(hsb[g * CC + c], k, acc[g]);
        }
        const float scale = nps[p] * 0.5f;  // OFFSET_SCALE = 0.5
        const float bias = off_b[t];
        const int didx = ((p * 8 + h) << 1) | xy;
#pragma unroll
        for (int g = 0; g < GQ; ++g) {
            const float4 r = *(const float4*)(refp + ((size_t)b * QQ + q0 + g) * 4);
            const float center = xy ? r.y : r.x;
            const float wh     = xy ? r.w : r.z;
            loc_t[((size_t)b * QQ + q0 + g) * 256 + didx] =
                fmaf((acc[g] + bias) * scale, wh, center);
        }
    } else {
        const int j = t - 256;             // 0..127 = h*16+p
        const int h = j >> 4;
        const int p = j & 15;
        const float* kcol = attn_k + j;
#pragma unroll 8
        for (int c = 0; c < CC; ++c) {
            const float k = kcol[c * 128];
#pragma unroll
            for (int g = 0; g < GQ; ++g)
                acc[g] = fmaf(hsb[g * CC + c], k, acc[g]);
        }
        const float bias = attn_b[j];
#pragma unroll
        for (int g = 0; g < GQ; ++g) {
            const float logit = acc[g] + bias;
            float m = logit;
#pragma unroll
            for (int o = 1; o < 16; o <<= 1)
                m = fmaxf(m, __shfl_xor(m, o));
            const float e = __expf(logit - m);
            float s = e;
#pragma unroll
            for (int o = 1; o < 16; o <<= 1)
                s += __shfl_xor(s, o);
            const float a = e / s;
            attn_out[((size_t)b * QQ + q0 + g) * 128 + j] = a;
            aw_t[((size_t)b * QQ + q0 + g) * 128 + p * 8 + h] = a;
        }
    }
}

// ---------------------------------------------------------------------------
// Kernel B v4: two-phase. Phase 1: one thread per (q,h,p) task computes the
// 4 bilinear weights (attn folded in, zeroed on OOB) and 4 clamped corner
// BYTE offsets -> LDS (removes the 8x redundant per-d-chunk weight math that
// made R3 VALU-issue-bound). Phase 2: wave = query; per point just
// 2 ds_read_b128 (8-way broadcast) + 4 addr adds + 4 float4 gathers +
// 16 FMAs. 4 queries/block, branchless, XCD-swizzled batches.
// ---------------------------------------------------------------------------
__global__ __launch_bounds__(256) void sample_kernel(
    const float* __restrict__ enc,    // (B,S,256)
    const float2* __restrict__ loc2,  // (B,Q,128) float2, [p*8+h]
    const float* __restrict__ aw_t,   // (B,Q,128), [p*8+h]
    float* __restrict__ out)          // (B,Q,256)
{
    __shared__ float4 sh_w[4 * 128];  // [qs][p*8+h] = {w00,w10,w01,w11}
    __shared__ int4   sh_o[4 * 128];  // [qs][p*8+h] = byte offsets

    const int g = blockIdx.x;              // 0..1199
    const int xcd = g & 7;
    const int i = g >> 3;                  // 0..149
    const int b = ((i & 1) << 3) | xcd;    // batch
    const int q0 = (i >> 1) * 4;           // 0..296
    const int qbase = b * QQ + q0;

    const int t = threadIdx.x;

    // ---- Phase 1: 512 tasks, 2 per thread ----
#pragma unroll
    for (int k = 0; k < 2; ++k) {
        const int tau = t + k * 256;       // qs = tau>>7, idx = tau&127 = p*8+h
        const int idx = tau & 127;
        const int p = idx >> 3;
        const int lvl = p >> 2;
        const int Wd = 80 >> lvl;
        const float Wf = (float)Wd;
        const int st = (25600 - (25600 >> (2 * lvl))) / 3;  // 0,6400,8000,8400

        const float2 l = loc2[(size_t)qbase * 128 + tau];
        const float  a = aw_t[(size_t)qbase * 128 + tau];

        const float x = l.x * Wf - 0.5f;
        const float y = l.y * Wf - 0.5f;
        const float x0f = floorf(x), y0f = floorf(y);
        const float lx = x - x0f, ly = y - y0f;
        const int x0 = (int)x0f, y0 = (int)y0f;
        const int x1 = x0 + 1, y1 = y0 + 1;

        const bool vx0 = (unsigned)x0 < (unsigned)Wd;
        const bool vx1 = (unsigned)x1 < (unsigned)Wd;
        const bool vy0 = (unsigned)y0 < (unsigned)Wd;
        const bool vy1 = (unsigned)y1 < (unsigned)Wd;

        const int x0c = min(max(x0, 0), Wd - 1);
        const int x1c = min(max(x1, 0), Wd - 1);
        const int y0c = min(max(y0, 0), Wd - 1);
        const int y1c = min(max(y1, 0), Wd - 1);

        float w00 = (1.f - lx) * (1.f - ly) * a;
        float w10 = lx * (1.f - ly) * a;
        float w01 = (1.f - lx) * ly * a;
        float w11 = lx * ly * a;
        w00 = (vx0 & vy0) ? w00 : 0.f;
        w10 = (vx1 & vy0) ? w10 : 0.f;
        w01 = (vx0 & vy1) ? w01 : 0.f;
        w11 = (vx1 & vy1) ? w11 : 0.f;

        const int r0 = (st + y0c * Wd) << 10;   // byte offsets (1024 B / pixel)
        const int r1 = (st + y1c * Wd) << 10;
        sh_w[tau] = make_float4(w00, w10, w01, w11);
        sh_o[tau] = make_int4(r0 + (x0c << 10), r0 + (x1c << 10),
                              r1 + (x0c << 10), r1 + (x1c << 10));
    }
    __syncthreads();

    // ---- Phase 2: wave = query, 16 points, minimal per-point work ----
    const int qs = t >> 6;
    const int lane = t & 63;
    const int h = lane >> 3;
    const int d4 = (lane & 7) << 2;
    const char* vb = (const char*)(enc + b * (SSS * 256) + h * 32 + d4);

    float4 acc = {0.f, 0.f, 0.f, 0.f};

#pragma unroll
    for (int p = 0; p < 16; ++p) {
        const float4 w = sh_w[qs * 128 + p * 8 + h];
        const int4   o = sh_o[qs * 128 + p * 8 + h];
        const float4 v00 = *(const float4*)(vb + o.x);
        const float4 v10 = *(const float4*)(vb + o.y);
        const float4 v01 = *(const float4*)(vb + o.z);
        const float4 v11 = *(const float4*)(vb + o.w);
        acc.x = fmaf(w.x, v00.x, fmaf(w.y, v10.x, fmaf(w.z, v01.x, fmaf(w.w, v11.x, acc.x))));
        acc.y = fmaf(w.x, v00.y, fmaf(w.y, v10.y, fmaf(w.z, v01.y, fmaf(w.w, v11.y, acc.y))));
        acc.z = fmaf(w.x, v00.z, fmaf(w.y, v10.z, fmaf(w.z, v01.z, fmaf(w.w, v11.z, acc.z))));
        acc.w = fmaf(w.x, v00.w, fmaf(w.y, v10.w, fmaf(w.z, v01.w, fmaf(w.w, v11.w, acc.w))));
    }

    float* op = out + (size_t)(qbase + qs) * 256 + h * 32 + d4;
    *(float4*)op = acc;
}

extern "C" void kernel_launch(void* const* d_in, const int* in_sizes, int n_in,
                              void* d_out, int out_size, void* d_ws, size_t ws_size,
                              hipStream_t stream) {
    const float* hs     = (const float*)d_in[0];
    const float* enc    = (const float*)d_in[1];
    const float* refp   = (const float*)d_in[2];
    const float* off_k  = (const float*)d_in[3];
    const float* off_b  = (const float*)d_in[4];
    const float* attn_k = (const float*)d_in[5];
    const float* attn_b = (const float*)d_in[6];
    const float* nps    = (const float*)d_in[7];

    float* out      = (float*)d_out;                       // B*Q*C
    float* attn_out = out + (size_t)BB * QQ * CC;          // B*Q*128
    float* loc_t    = (float*)d_ws;                        // B*Q*256 floats
    float* aw_t     = loc_t + (size_t)BB * QQ * 256;       // B*Q*128 floats

    precompute_kernel<<<BB * QT, 384, 0, stream>>>(hs, refp, off_k, off_b,
                                                   attn_k, attn_b, nps,
                                                   loc_t, aw_t, attn_out);
    sample_kernel<<<BB * (QQ / 4), 256, 0, stream>>>(enc, (const float2*)loc_t,
                                                     aw_t, out);
}